// Round 15
// baseline (438.280 us; speedup 1.0000x reference)
//
#include <hip/hip_runtime.h>
#include <hip/hip_bf16.h>

typedef __hip_bfloat16 bf16;
typedef __attribute__((ext_vector_type(8))) short short8;
typedef __attribute__((ext_vector_type(4))) short s4v;
typedef __attribute__((ext_vector_type(4))) float float4v;

#define NN 512      // image N
#define NA 30       // angles
#define ND 729      // detectors
#define NB 2        // batch
#define NL 3        // iterations
#define BNN (NB*NN*NN)     // 524288
#define BAD (NB*NA*ND)     // 43740

// padded image layout: PH x PW, logical (0,0) at physical (2,2)
#define PW 520
#define PH 516
#define PIMG (PH*PW)       // 268320
#define POFF (2*PW + 2)    // 1042

// ---- workspace float offsets ----
#define O_CS  0
#define O_SN  32
#define O_ICS 64                      // 1/cs per angle
#define O_ISN 96                      // -1/sn per angle
#define O_XP  128                     // 2*PIMG  (current X, padded)
#define O_YP  (O_XP + 2*PIMG)         // 2*PIMG  (Y = X + noise, padded)
#define O_SP  (O_YP + 2*PIMG)         // BAD
#define O_Q   (O_SP + BAD)            // BAD
#define O_WR  (O_Q + BAD)             // bf16 region: 69120 bf16 = 34560 floats
#define O_H   (((O_WR + 34560) + 15) & ~15)
#define H_FLOATS (NB * 32 * NN * NN / 2)

// repacked weight bf16 offsets within WR region
#define WR2_OFF 0                   // [n][tap][co32][ci32] : 3*9216
#define WR3_OFF 27648               // 3*9216
#define WR4_OFF 55296               // [n][tap][co16][ci32] : 3*4608 (co>0 zero)

// unaligned 8B load (pair of adjacent floats) -> global_load_dwordx2
__device__ __forceinline__ float2 ld2u(const float* p)
{
    float2 r;
    __builtin_memcpy(&r, p, 8);
    return r;
}

// ---- setup: angles + reciprocals + weight repack + image padding, one kernel ----
__global__ void k_prep(const float* __restrict__ theta,
                       const float* __restrict__ w2, const float* __restrict__ w3,
                       const float* __restrict__ w4, const float* __restrict__ x0,
                       float* __restrict__ ws, bf16* __restrict__ wr)
{
    int idx = blockIdx.x * 256 + threadIdx.x;
    if (idx < NA) {
        float t = theta[idx];
        float cs = cosf(t), sn = sinf(t);
        ws[O_CS + idx] = cs;
        ws[O_SN + idx] = sn;
        ws[O_ICS + idx] = 1.0f / cs;      // +-inf ok
        ws[O_ISN + idx] = -1.0f / sn;     // +-inf ok
    }
    if (idx < 2 * 27648) {
        const float* w = (idx < 27648) ? w2 : w3;
        int base = (idx < 27648) ? WR2_OFF : WR3_OFF;
        int r = idx % 27648;
        int n = r / 9216; int r2 = r % 9216;
        int tap = r2 / 1024; int r3 = r2 % 1024;
        int co = r3 / 32, ci = r3 % 32;
        wr[base + r] = __float2bfloat16(w[n * 9216 + (co * 32 + ci) * 9 + tap]);
    } else if (idx < 2 * 27648 + 3 * 4608) {
        int r = idx - 2 * 27648;
        int n = r / 4608; int r2 = r % 4608;
        int tap = r2 / 512; int r3 = r2 % 512;
        int co = r3 / 32, ci = r3 % 32;
        float v = (co == 0) ? w4[n * 288 + ci * 9 + tap] : 0.f;
        wr[WR4_OFF + r] = __float2bfloat16(v);
    }
    if (idx < 2 * PIMG) {
        int b = idx / PIMG, p = idx % PIMG;
        int y = p / PW, x = p % PW;
        bool interior = (y >= 2 && y < 2 + NN && x >= 2 && x < 2 + NN);
        float v = interior ? x0[b * NN * NN + (y - 2) * NN + (x - 2)] : 0.f;
        ws[O_XP + idx] = v;
        if (!interior) ws[O_YP + idx] = 0.f;
    }
}

// intersect t-interval with constraint lo < A + tc*coef < hi, via inv = 1/coef
__device__ __forceinline__ void isect2(float A, float inv, float lo, float hi,
                                       float& tlo, float& thi)
{
    float a = (lo - A) * inv, b = (hi - A) * inv;
    tlo = fmaxf(tlo, fminf(a, b));   // NaN (0*inf) dropped by fmin/fmax -> safe
    thi = fminf(thi, fmaxf(a, b));
}

// ---- radon forward: ONE ray (s) per wave, 64 t-lanes; chord-clipped ----
// (r12 structure: best measured. paired dwordx2 loads, reciprocal clipping.)
__global__ __launch_bounds__(256) void k_radon(const float* __restrict__ img,
    const float* __restrict__ ws, float* __restrict__ out)
{
    int b = blockIdx.z, a = blockIdx.y;
    int wave = threadIdx.x >> 6;
    int lane = threadIdx.x & 63;
    int s = blockIdx.x * 4 + wave;
    if (s >= ND) return;
    float cs = ws[O_CS + a], sn = ws[O_SN + a];
    float ics = ws[O_ICS + a], isn = ws[O_ISN + a];
    float s_c = (float)s - 364.0f;
    float A_r = 255.5f + s_c * sn;    // r(t) = A_r + tc*cs
    float A_c = 255.5f + s_c * cs;    // c(t) = A_c - tc*sn

    float tlo = -1e9f, thi = 1e9f;
    isect2(A_r, ics, -1.0f, 512.0f, tlo, thi);
    isect2(A_c, isn, -1.0f, 512.0f, tlo, thi);
    float t0f = fmaxf(tlo + 364.0f, 0.0f);
    float t1f = fminf(thi + 364.0f, 728.0f);

    float acc = 0.f;
    if (t0f <= t1f) {
        int tb = (int)ceilf(t0f);
        int te = (int)floorf(t1f);
        const float* im = img + b * PIMG;
#pragma unroll 2
        for (int t = tb + lane; t <= te; t += 64) {
            float tc = (float)t - 364.0f;
            float r = fmaf(tc, cs, A_r);
            float c = fmaf(-tc, sn, A_c);
            float rf = floorf(r), cf = floorf(c);
            float dr = r - rf, dc = c - cf;
            int idx = (int)rf * PW + (int)cf;
            float2 tp = ld2u(im + idx);
            float2 bt = ld2u(im + idx + PW);
            float top = fmaf(dc, tp.y - tp.x, tp.x);
            float bot = fmaf(dc, bt.y - bt.x, bt.x);
            acc = fmaf(dr, bot - top, acc + top);
        }
    }
    acc += __shfl_down(acc, 32, 64);
    acc += __shfl_down(acc, 16, 64);
    acc += __shfl_down(acc, 8, 64);
    acc += __shfl_down(acc, 4, 64);
    acc += __shfl_down(acc, 2, 64);
    acc += __shfl_down(acc, 1, 64);
    if (lane == 0) out[(b * NA + a) * ND + s] = acc;
}

// ---- ramp filter as direct odd-tap convolution: q = sino - scale*conv(sp) ----
__global__ void k_filter(const float* __restrict__ sp, const float* __restrict__ sino,
                         float* __restrict__ q)
{
    __shared__ float row[ND];
    __shared__ float taps[364];
    int ba = blockIdx.y;
    const float* src = sp + ba * ND;
    for (int i = threadIdx.x; i < ND; i += 256) row[i] = src[i];
    const float PI2 = 9.86960440108936f;
    for (int i = threadIdx.x; i < 364; i += 256) {
        float m = (float)(2 * i + 1);
        taps[i] = -2.0f / (PI2 * m * m);
    }
    __syncthreads();
    const float scale = 0.0523598775598299f;  // pi/(2A)
    int d = blockIdx.x * 256 + threadIdx.x;
    if (d < ND) {
        float g0 = 0.5f * row[d], g1 = 0.f;
#pragma unroll 4
        for (int j = 0; j < 364; j += 2) {
            int m0 = 2 * j + 1, m1 = 2 * j + 3;
            float l0 = (d - m0 >= 0) ? row[d - m0] : 0.f;
            float r0 = (d + m0 < ND) ? row[d + m0] : 0.f;
            g0 = fmaf(taps[j], l0 + r0, g0);
            float l1 = (d - m1 >= 0) ? row[d - m1] : 0.f;
            float r1 = (d + m1 < ND) ? row[d + m1] : 0.f;
            g1 = fmaf(taps[j + 1], l1 + r1, g1);
        }
        q[ba * ND + d] = sino[ba * ND + d] - scale * (g0 + g1);
    }
}

// ---- LDS-tiled backprojection + update:  out = src1 + steps[n]*bp(q) ----
__global__ __launch_bounds__(256) void k_backproj_update(const float* __restrict__ q,
    const float* __restrict__ src1, const float* __restrict__ ws,
    const float* __restrict__ steps, int n, float* __restrict__ out,
    float* __restrict__ outcopy)
{
    __shared__ float qt[NA][28];
    __shared__ int dmin_s[NA];
    int b = blockIdx.z;
    int x0 = blockIdx.x * 16, y0 = blockIdx.y * 16;
    int tid = threadIdx.x;
    int lx = tid & 15, ly = tid >> 4;
    const float* qb = q + b * NA * ND;

    for (int idx = tid; idx < NA * 26; idx += 256) {
        int a = idx / 26, j = idx % 26;
        float cs = ws[O_CS + a], sn = ws[O_SN + a];
        float f00 = fmaf(cs, (float)x0 - 255.5f, fmaf(sn, (float)y0 - 255.5f, 364.0f));
        float fmn = f00 + fminf(cs * 15.f, 0.f) + fminf(sn * 15.f, 0.f);
        int dm = (int)floorf(fmn);
        if (j == 0) dmin_s[a] = dm;
        int d = dm + j;
        qt[a][j] = (d >= 0 && d < ND) ? qb[a * ND + d] : 0.f;
    }
    __syncthreads();

    float xc = (float)(x0 + lx) - 255.5f, yc = (float)(y0 + ly) - 255.5f;
    float acc = 0.f;
#pragma unroll
    for (int a = 0; a < NA; a++) {
        float cs = ws[O_CS + a], sn = ws[O_SN + a];
        float f = fmaf(cs, xc, fmaf(sn, yc, 364.0f));
        float lf = floorf(f);
        float w = f - lf;
        int j = (int)lf - dmin_s[a];
        float v0 = qt[a][j], v1 = qt[a][j + 1];
        acc = fmaf(v0, 1.0f - w, fmaf(v1, w, acc));
    }
    int pidx = b * PIMG + (y0 + ly) * PW + (x0 + lx);
    float v = fmaf(steps[n], acc, src1[pidx]);
    out[pidx] = v;
    if (outcopy) {
        int fidx = b * NN * NN + (y0 + ly) * NN + (x0 + lx);
        outcopy[fidx] = v;
        outcopy[fidx + BNN] = v;
        outcopy[fidx + 2 * BNN] = v;
    }
}

// ---- FUSED conv1+conv2: XP -> (h1 halo tile in LDS) -> h2 (HWC bf16 global) ----
__global__ __launch_bounds__(256) void k_conv12(const float* __restrict__ XPb,
    const float* __restrict__ W1, const float* __restrict__ B1,
    const bf16* __restrict__ Wr2, const float* __restrict__ B2,
    bf16* __restrict__ outb)
{
    __shared__ bf16 h1t[34][18][32];
    int b = blockIdx.z;
    int x0 = blockIdx.x * 16;
    int Y0 = blockIdx.y * 32;
    const float* in = XPb + b * PIMG;      // origin-adjusted padded

    // ---- phase A: h1 on halo [Y0-1, Y0+33) x [x0-1, x0+17) ----
    for (int p = threadIdx.x; p < 34 * 18; p += 256) {
        int yy = p / 18, xx = p % 18;
        int gy = Y0 + yy - 1, gx = x0 + xx - 1;
        if (gy < 0 || gy >= NN || gx < 0 || gx >= NN) {
#pragma unroll
            for (int g = 0; g < 4; g++)
                *(short8*)(&h1t[yy][xx][g * 8]) = short8{};
        } else {
            float v[9];
#pragma unroll
            for (int dy = 0; dy < 3; dy++)
#pragma unroll
                for (int dx = 0; dx < 3; dx++)
                    v[dy * 3 + dx] = in[(gy + dy - 1) * PW + (gx + dx - 1)];
#pragma unroll
            for (int g = 0; g < 4; g++) {
                short8 pk;
#pragma unroll
                for (int j = 0; j < 8; j++) {
                    int co = g * 8 + j;
                    float a = B1[co];
                    const float* w = W1 + co * 9;   // block-uniform -> s_load
#pragma unroll
                    for (int k = 0; k < 9; k++) a = fmaf(v[k], w[k], a);
                    a = fmaxf(a, 0.f);
                    bf16 h = __float2bfloat16(a);
                    pk[j] = *reinterpret_cast<short*>(&h);
                }
                *(short8*)(&h1t[yy][xx][g * 8]) = pk;
            }
        }
    }
    __syncthreads();

    // ---- phase B: conv2 (MFMA), h1 from LDS ----
    int lane = threadIdx.x & 63;
    int wave = threadIdx.x >> 6;
    int n16 = lane & 15, quad = lane >> 4;
    int y0w = Y0 + wave * 8;

    short8 wf[18];
#pragma unroll
    for (int tap = 0; tap < 9; tap++)
#pragma unroll
        for (int t = 0; t < 2; t++)
            wf[tap * 2 + t] = *(const short8*)(Wr2 + ((tap * 2 + t) * 16 + n16) * 32 + quad * 8);

    short8 win[3][3];
    auto loadrow = [&](int yy, short8* dst) {
        int ly = yy - (Y0 - 1);   // always in [0,34)
#pragma unroll
        for (int dx = 0; dx < 3; dx++)
            dst[dx] = *(const short8*)(&h1t[ly][n16 + dx][quad * 8]);
    };
    loadrow(y0w - 1, win[0]);
    loadrow(y0w,     win[1]);

    float4v bias[2];
#pragma unroll
    for (int t = 0; t < 2; t++)
        bias[t] = *(const float4v*)(B2 + t * 16 + quad * 4);

    bf16* out = outb + (size_t)b * NN * NN * 32;
#pragma unroll
    for (int i = 0; i < 8; i++) {
        int y = y0w + i;
        loadrow(y + 1, win[(i + 2) % 3]);
        float4v acc[2];
#pragma unroll
        for (int t = 0; t < 2; t++) acc[t] = bias[t];
#pragma unroll
        for (int dy = 0; dy < 3; dy++) {
            short8* row = win[(i + dy) % 3];
#pragma unroll
            for (int dx = 0; dx < 3; dx++) {
                int tap = dy * 3 + dx;
#pragma unroll
                for (int t = 0; t < 2; t++)
                    acc[t] = __builtin_amdgcn_mfma_f32_16x16x32_bf16(wf[tap * 2 + t], row[dx], acc[t], 0, 0, 0);
            }
        }
        bf16* pp = out + ((size_t)y * NN + x0 + n16) * 32 + quad * 4;
#pragma unroll
        for (int t = 0; t < 2; t++) {
            s4v pk;
#pragma unroll
            for (int r = 0; r < 4; r++) {
                float v = fmaxf(acc[t][r], 0.f);
                bf16 h = __float2bfloat16(v);
                pk[r] = *reinterpret_cast<short*>(&h);
            }
            *(s4v*)(pp + t * 16) = pk;
        }
    }
}

// ---- FUSED conv3+conv4: h2 -> (h1 halo tile in LDS, MFMA) -> YP = XP + conv4 ----
// Phase A: conv3 on halo 18x34 via two overlapping 16-px x-strips x two 17-row
// halves (wave = strip + 2*half); strip1 lanes n16>=14 write the 2 extra cols.
// Phase B: conv4 (NCO=1) from LDS, no bounds checks; epilogue adds XP.
__global__ __launch_bounds__(256) void k_conv34(const bf16* __restrict__ h2b,
    const bf16* __restrict__ Wr3, const float* __restrict__ B3,
    const bf16* __restrict__ Wr4, const float* __restrict__ XPb,
    float* __restrict__ YPb)
{
    __shared__ bf16 h1t[34][18][32];
    int b = blockIdx.z;
    int x0 = blockIdx.x * 16;
    int Y0 = blockIdx.y * 32;
    const bf16* in = h2b + (size_t)b * NN * NN * 32;

    int lane = threadIdx.x & 63;
    int wave = threadIdx.x >> 6;
    int n16 = lane & 15, quad = lane >> 4;

    // ---- phase A: conv3 -> h1 halo [Y0-1,Y0+33) x [x0-1,x0+17) in LDS ----
    {
        int strip = wave & 1, half = wave >> 1;
        int sx = x0 - 1 + strip * 2;      // strip x start (16 px from sx)
        int ly0 = half * 17;
        int gy0 = Y0 - 1 + ly0;

        short8 wf[18];
#pragma unroll
        for (int tap = 0; tap < 9; tap++)
#pragma unroll
            for (int t = 0; t < 2; t++)
                wf[tap * 2 + t] = *(const short8*)(Wr3 + ((tap * 2 + t) * 16 + n16) * 32 + quad * 8);

        bool vx[3];
#pragma unroll
        for (int dx = 0; dx < 3; dx++) {
            int xx = sx + n16 + dx - 1;
            vx[dx] = (xx >= 0) && (xx < NN);
        }
        short8 win[3][3];
        auto loadrow = [&](int yy, short8* dst) {
            if (yy >= 0 && yy < NN) {
                const bf16* rowp = in + (size_t)yy * NN * 32;
#pragma unroll
                for (int dx = 0; dx < 3; dx++) {
                    short8 v = {};
                    if (vx[dx]) v = *(const short8*)(rowp + (sx + n16 + dx - 1) * 32 + quad * 8);
                    dst[dx] = v;
                }
            } else {
                dst[0] = short8{}; dst[1] = short8{}; dst[2] = short8{};
            }
        };
        loadrow(gy0 - 1, win[0]);
        loadrow(gy0,     win[1]);

        float4v bias[2];
#pragma unroll
        for (int t = 0; t < 2; t++)
            bias[t] = *(const float4v*)(B3 + t * 16 + quad * 4);

        bool wr = (strip == 0) || (n16 >= 14);
        int px = n16 + strip * 2;
        for (int i = 0; i < 17; i++) {
            int y = gy0 + i;
            loadrow(y + 1, win[(i + 2) % 3]);
            float4v acc[2];
#pragma unroll
            for (int t = 0; t < 2; t++) acc[t] = bias[t];
#pragma unroll
            for (int dy = 0; dy < 3; dy++) {
                short8* row = win[(i + dy) % 3];
#pragma unroll
                for (int dx = 0; dx < 3; dx++) {
                    int tap = dy * 3 + dx;
#pragma unroll
                    for (int t = 0; t < 2; t++)
                        acc[t] = __builtin_amdgcn_mfma_f32_16x16x32_bf16(wf[tap * 2 + t], row[dx], acc[t], 0, 0, 0);
                }
            }
            if (wr) {
                int ly = ly0 + i;
#pragma unroll
                for (int t = 0; t < 2; t++) {
                    s4v pk;
#pragma unroll
                    for (int r = 0; r < 4; r++) {
                        float v = fmaxf(acc[t][r], 0.f);
                        bf16 h = __float2bfloat16(v);
                        pk[r] = *reinterpret_cast<short*>(&h);
                    }
                    *(s4v*)(&h1t[ly][px][t * 16 + quad * 4]) = pk;
                }
            }
        }
    }
    __syncthreads();

    // ---- phase B: conv4 (NCO=1) from LDS; YP = XP + conv4(h1) ----
    {
        int y0w = Y0 + wave * 8;
        short8 wf[9];
#pragma unroll
        for (int tap = 0; tap < 9; tap++)
            wf[tap] = *(const short8*)(Wr4 + (tap * 16 + n16) * 32 + quad * 8);

        short8 win[3][3];
        auto ldsrow = [&](int yy, short8* dst) {
            int ly = yy - (Y0 - 1);   // always in [0,34)
#pragma unroll
            for (int dx = 0; dx < 3; dx++)
                dst[dx] = *(const short8*)(&h1t[ly][n16 + dx][quad * 8]);
        };
        ldsrow(y0w - 1, win[0]);
        ldsrow(y0w,     win[1]);

        const float* xp = XPb + b * PIMG;
        float* yp = YPb + b * PIMG;
#pragma unroll
        for (int i = 0; i < 8; i++) {
            int y = y0w + i;
            ldsrow(y + 1, win[(i + 2) % 3]);
            float4v acc = {0.f, 0.f, 0.f, 0.f};
#pragma unroll
            for (int dy = 0; dy < 3; dy++) {
                short8* row = win[(i + dy) % 3];
#pragma unroll
                for (int dx = 0; dx < 3; dx++)
                    acc = __builtin_amdgcn_mfma_f32_16x16x32_bf16(wf[dy * 3 + dx], row[dx], acc, 0, 0, 0);
            }
            if (quad == 0) {
                int pi = y * PW + x0 + n16;
                yp[pi] = xp[pi] + acc[0];
            }
        }
    }
}

extern "C" void kernel_launch(void* const* d_in, const int* in_sizes, int n_in,
                              void* d_out, int out_size, void* d_ws, size_t ws_size,
                              hipStream_t stream)
{
    const float* x0    = (const float*)d_in[1];
    const float* sg    = (const float*)d_in[2];
    const float* theta = (const float*)d_in[3];
    const float* w1    = (const float*)d_in[5];
    const float* b1    = (const float*)d_in[6];
    const float* w2    = (const float*)d_in[7];
    const float* b2    = (const float*)d_in[8];
    const float* w3    = (const float*)d_in[9];
    const float* b3    = (const float*)d_in[10];
    const float* w4    = (const float*)d_in[11];
    const float* steps = (const float*)d_in[12];

    float* ws = (float*)d_ws;
    float* XP = ws + O_XP + POFF;     // origin-adjusted padded pointers
    float* YP = ws + O_YP + POFF;
    float* SP = ws + O_SP;
    float* Q  = ws + O_Q;
    bf16* wr  = (bf16*)(ws + O_WR);
    bf16* h2  = (bf16*)(ws + O_H);

    k_prep<<<(2 * PIMG + 255) / 256, 256, 0, stream>>>(theta, w2, w3, w4, x0, ws, wr);

    for (int n = 0; n < NL; n++) {
        // denoiser: fused conv1+2 (XP -> h2), fused conv3+4 (h2 -> YP = XP + noise)
        k_conv12<<<dim3(32, 16, NB), 256, 0, stream>>>(
            XP, w1 + n * 288, b1 + n * 32, wr + WR2_OFF + n * 9216, b2 + n * 32, h2);
        k_conv34<<<dim3(32, 16, NB), 256, 0, stream>>>(
            h2, wr + WR3_OFF + n * 9216, b3 + n * 32, wr + WR4_OFF + n * 4608, XP, YP);

        // fused physics path (linearity): XP = YP + steps[n]*bp(sino - F(R(YP)))
        k_radon<<<dim3((ND + 3) / 4, NA, NB), 256, 0, stream>>>(YP, ws, SP);
        k_filter<<<dim3(3, NB * NA), 256, 0, stream>>>(SP, sg, Q);
        k_backproj_update<<<dim3(32, 32, NB), 256, 0, stream>>>(
            Q, YP, ws, steps, n, XP, (n == NL - 1) ? (float*)d_out : nullptr);
    }
}

// Round 16
// 417.833 us; speedup vs baseline: 1.0489x; 1.0489x over previous
//
#include <hip/hip_runtime.h>
#include <hip/hip_bf16.h>

typedef __hip_bfloat16 bf16;
typedef __attribute__((ext_vector_type(8))) short short8;
typedef __attribute__((ext_vector_type(4))) short s4v;
typedef __attribute__((ext_vector_type(4))) float float4v;

#define NN 512      // image N
#define NA 30       // angles
#define ND 729      // detectors
#define NB 2        // batch
#define NL 3        // iterations
#define BNN (NB*NN*NN)     // 524288
#define BAD (NB*NA*ND)     // 43740

// padded image layout: PH x PW, logical (0,0) at physical (2,2)
#define PW 520
#define PH 516
#define PIMG (PH*PW)       // 268320
#define POFF (2*PW + 2)    // 1042

// ---- workspace float offsets ----
#define O_CS  0
#define O_SN  32
#define O_ICS 64                      // 1/cs per angle
#define O_ISN 96                      // -1/sn per angle
#define O_XP  128                     // 2*PIMG  (current X, padded)
#define O_YP  (O_XP + 2*PIMG)         // 2*PIMG  (Y = X + noise, padded)
#define O_YPT (O_YP + 2*PIMG)         // 2*PIMG  (transposed Y, padded)
#define O_SP  (O_YPT + 2*PIMG)        // BAD
#define O_Q   (O_SP + BAD)            // BAD
#define O_WR  (O_Q + BAD)             // bf16 region: 69120 bf16 = 34560 floats
#define O_H   (((O_WR + 34560) + 15) & ~15)
#define H_FLOATS (NB * 32 * NN * NN / 2)

// repacked weight bf16 offsets within WR region
#define WR2_OFF 0                   // [n][tap][co32][ci32] : 3*9216
#define WR3_OFF 27648               // 3*9216
#define WR4_OFF 55296               // [n][tap][co16][ci32] : 3*4608 (co>0 zero)

// unaligned 8B load (pair of adjacent floats) -> global_load_dwordx2
__device__ __forceinline__ float2 ld2u(const float* p)
{
    float2 r;
    __builtin_memcpy(&r, p, 8);
    return r;
}

// ---- setup: angles + reciprocals + weight repack + image padding, one kernel ----
__global__ void k_prep(const float* __restrict__ theta,
                       const float* __restrict__ w2, const float* __restrict__ w3,
                       const float* __restrict__ w4, const float* __restrict__ x0,
                       float* __restrict__ ws, bf16* __restrict__ wr)
{
    int idx = blockIdx.x * 256 + threadIdx.x;
    if (idx < NA) {
        float t = theta[idx];
        float cs = cosf(t), sn = sinf(t);
        ws[O_CS + idx] = cs;
        ws[O_SN + idx] = sn;
        ws[O_ICS + idx] = 1.0f / cs;      // +-inf ok
        ws[O_ISN + idx] = -1.0f / sn;     // +-inf ok
    }
    if (idx < 2 * 27648) {
        const float* w = (idx < 27648) ? w2 : w3;
        int base = (idx < 27648) ? WR2_OFF : WR3_OFF;
        int r = idx % 27648;
        int n = r / 9216; int r2 = r % 9216;
        int tap = r2 / 1024; int r3 = r2 % 1024;
        int co = r3 / 32, ci = r3 % 32;
        wr[base + r] = __float2bfloat16(w[n * 9216 + (co * 32 + ci) * 9 + tap]);
    } else if (idx < 2 * 27648 + 3 * 4608) {
        int r = idx - 2 * 27648;
        int n = r / 4608; int r2 = r % 4608;
        int tap = r2 / 512; int r3 = r2 % 512;
        int co = r3 / 32, ci = r3 % 32;
        float v = (co == 0) ? w4[n * 288 + ci * 9 + tap] : 0.f;
        wr[WR4_OFF + r] = __float2bfloat16(v);
    }
    if (idx < 2 * PIMG) {
        int b = idx / PIMG, p = idx % PIMG;
        int y = p / PW, x = p % PW;
        bool interior = (y >= 2 && y < 2 + NN && x >= 2 && x < 2 + NN);
        float v = interior ? x0[b * NN * NN + (y - 2) * NN + (x - 2)] : 0.f;
        ws[O_XP + idx] = v;
        if (!interior) {
            ws[O_YP + idx] = 0.f;
            ws[O_YPT + idx] = 0.f;
        }
    }
}

// intersect t-interval with constraint lo < A + tc*coef < hi, via inv = 1/coef
__device__ __forceinline__ void isect2(float A, float inv, float lo, float hi,
                                       float& tlo, float& thi)
{
    float a = (lo - A) * inv, b = (hi - A) * inv;
    tlo = fmaxf(tlo, fminf(a, b));   // NaN (0*inf) dropped by fmin/fmax -> safe
    thi = fminf(thi, fmaxf(a, b));
}

// ---- radon forward: ONE ray (s) per wave, 64 t-lanes; chord-clipped ----
// Angle-adaptive layout: sample transposed copy when |cs| >= |sn| so rows
// crossed per 64-lane load = 64*min(|cs|,|sn|) -> ~2x fewer L1 line touches.
__global__ __launch_bounds__(256) void k_radon(const float* __restrict__ img,
    const float* __restrict__ imgT, const float* __restrict__ ws,
    float* __restrict__ out)
{
    int b = blockIdx.z, a = blockIdx.y;
    int wave = threadIdx.x >> 6;
    int lane = threadIdx.x & 63;
    int s = blockIdx.x * 4 + wave;
    if (s >= ND) return;
    float cs = ws[O_CS + a], sn = ws[O_SN + a];
    float ics = ws[O_ICS + a], isn = ws[O_ISN + a];
    float s_c = (float)s - 364.0f;
    float A_r = 255.5f + s_c * sn;    // r(t) = A_r + tc*cs
    float A_c = 255.5f + s_c * cs;    // c(t) = A_c - tc*sn

    float tlo = -1e9f, thi = 1e9f;
    isect2(A_r, ics, -1.0f, 512.0f, tlo, thi);
    isect2(A_c, isn, -1.0f, 512.0f, tlo, thi);
    float t0f = fmaxf(tlo + 364.0f, 0.0f);
    float t1f = fminf(thi + 364.0f, 728.0f);

    bool useT = fabsf(cs) >= fabsf(sn);   // wave-uniform
    const float* im = (useT ? imgT : img) + b * PIMG;

    float acc = 0.f;
    if (t0f <= t1f) {
        int tb = (int)ceilf(t0f);
        int te = (int)floorf(t1f);
#pragma unroll 2
        for (int t = tb + lane; t <= te; t += 64) {
            float tc = (float)t - 364.0f;
            float r = fmaf(tc, cs, A_r);
            float c = fmaf(-tc, sn, A_c);
            float rf = floorf(r), cf = floorf(c);
            float dr = r - rf, dc = c - cf;
            int irr = (int)rf, icc = (int)cf;
            int idx = useT ? (icc * PW + irr) : (irr * PW + icc);
            float da = useT ? dr : dc;
            float db = useT ? dc : dr;
            float2 p1 = ld2u(im + idx);
            float2 p2 = ld2u(im + idx + PW);
            float u = fmaf(da, p1.y - p1.x, p1.x);
            float w = fmaf(da, p2.y - p2.x, p2.x);
            acc = fmaf(db, w - u, acc + u);
        }
    }
    acc += __shfl_down(acc, 32, 64);
    acc += __shfl_down(acc, 16, 64);
    acc += __shfl_down(acc, 8, 64);
    acc += __shfl_down(acc, 4, 64);
    acc += __shfl_down(acc, 2, 64);
    acc += __shfl_down(acc, 1, 64);
    if (lane == 0) out[(b * NA + a) * ND + s] = acc;
}

// ---- ramp filter as direct odd-tap convolution: q = sino - scale*conv(sp) ----
__global__ void k_filter(const float* __restrict__ sp, const float* __restrict__ sino,
                         float* __restrict__ q)
{
    __shared__ float row[ND];
    __shared__ float taps[364];
    int ba = blockIdx.y;
    const float* src = sp + ba * ND;
    for (int i = threadIdx.x; i < ND; i += 256) row[i] = src[i];
    const float PI2 = 9.86960440108936f;
    for (int i = threadIdx.x; i < 364; i += 256) {
        float m = (float)(2 * i + 1);
        taps[i] = -2.0f / (PI2 * m * m);
    }
    __syncthreads();
    const float scale = 0.0523598775598299f;  // pi/(2A)
    int d = blockIdx.x * 256 + threadIdx.x;
    if (d < ND) {
        float g0 = 0.5f * row[d], g1 = 0.f;
#pragma unroll 4
        for (int j = 0; j < 364; j += 2) {
            int m0 = 2 * j + 1, m1 = 2 * j + 3;
            float l0 = (d - m0 >= 0) ? row[d - m0] : 0.f;
            float r0 = (d + m0 < ND) ? row[d + m0] : 0.f;
            g0 = fmaf(taps[j], l0 + r0, g0);
            float l1 = (d - m1 >= 0) ? row[d - m1] : 0.f;
            float r1 = (d + m1 < ND) ? row[d + m1] : 0.f;
            g1 = fmaf(taps[j + 1], l1 + r1, g1);
        }
        q[ba * ND + d] = sino[ba * ND + d] - scale * (g0 + g1);
    }
}

// ---- LDS-tiled backprojection + update:  out = src1 + steps[n]*bp(q) ----
__global__ __launch_bounds__(256) void k_backproj_update(const float* __restrict__ q,
    const float* __restrict__ src1, const float* __restrict__ ws,
    const float* __restrict__ steps, int n, float* __restrict__ out,
    float* __restrict__ outcopy)
{
    __shared__ float qt[NA][28];
    __shared__ int dmin_s[NA];
    int b = blockIdx.z;
    int x0 = blockIdx.x * 16, y0 = blockIdx.y * 16;
    int tid = threadIdx.x;
    int lx = tid & 15, ly = tid >> 4;
    const float* qb = q + b * NA * ND;

    for (int idx = tid; idx < NA * 26; idx += 256) {
        int a = idx / 26, j = idx % 26;
        float cs = ws[O_CS + a], sn = ws[O_SN + a];
        float f00 = fmaf(cs, (float)x0 - 255.5f, fmaf(sn, (float)y0 - 255.5f, 364.0f));
        float fmn = f00 + fminf(cs * 15.f, 0.f) + fminf(sn * 15.f, 0.f);
        int dm = (int)floorf(fmn);
        if (j == 0) dmin_s[a] = dm;
        int d = dm + j;
        qt[a][j] = (d >= 0 && d < ND) ? qb[a * ND + d] : 0.f;
    }
    __syncthreads();

    float xc = (float)(x0 + lx) - 255.5f, yc = (float)(y0 + ly) - 255.5f;
    float acc = 0.f;
#pragma unroll
    for (int a = 0; a < NA; a++) {
        float cs = ws[O_CS + a], sn = ws[O_SN + a];
        float f = fmaf(cs, xc, fmaf(sn, yc, 364.0f));
        float lf = floorf(f);
        float w = f - lf;
        int j = (int)lf - dmin_s[a];
        float v0 = qt[a][j], v1 = qt[a][j + 1];
        acc = fmaf(v0, 1.0f - w, fmaf(v1, w, acc));
    }
    int pidx = b * PIMG + (y0 + ly) * PW + (x0 + lx);
    float v = fmaf(steps[n], acc, src1[pidx]);
    out[pidx] = v;
    if (outcopy) {
        int fidx = b * NN * NN + (y0 + ly) * NN + (x0 + lx);
        outcopy[fidx] = v;
        outcopy[fidx + BNN] = v;
        outcopy[fidx + 2 * BNN] = v;
    }
}

// ---- FUSED conv1+conv2: XP -> (h1 halo tile in LDS) -> h2 (HWC bf16 global) ----
__global__ __launch_bounds__(256) void k_conv12(const float* __restrict__ XPb,
    const float* __restrict__ W1, const float* __restrict__ B1,
    const bf16* __restrict__ Wr2, const float* __restrict__ B2,
    bf16* __restrict__ outb)
{
    __shared__ bf16 h1t[34][18][32];
    int b = blockIdx.z;
    int x0 = blockIdx.x * 16;
    int Y0 = blockIdx.y * 32;
    const float* in = XPb + b * PIMG;      // origin-adjusted padded

    // ---- phase A: h1 on halo [Y0-1, Y0+33) x [x0-1, x0+17) ----
    for (int p = threadIdx.x; p < 34 * 18; p += 256) {
        int yy = p / 18, xx = p % 18;
        int gy = Y0 + yy - 1, gx = x0 + xx - 1;
        if (gy < 0 || gy >= NN || gx < 0 || gx >= NN) {
#pragma unroll
            for (int g = 0; g < 4; g++)
                *(short8*)(&h1t[yy][xx][g * 8]) = short8{};
        } else {
            float v[9];
#pragma unroll
            for (int dy = 0; dy < 3; dy++)
#pragma unroll
                for (int dx = 0; dx < 3; dx++)
                    v[dy * 3 + dx] = in[(gy + dy - 1) * PW + (gx + dx - 1)];
#pragma unroll
            for (int g = 0; g < 4; g++) {
                short8 pk;
#pragma unroll
                for (int j = 0; j < 8; j++) {
                    int co = g * 8 + j;
                    float a = B1[co];
                    const float* w = W1 + co * 9;   // block-uniform -> s_load
#pragma unroll
                    for (int k = 0; k < 9; k++) a = fmaf(v[k], w[k], a);
                    a = fmaxf(a, 0.f);
                    bf16 h = __float2bfloat16(a);
                    pk[j] = *reinterpret_cast<short*>(&h);
                }
                *(short8*)(&h1t[yy][xx][g * 8]) = pk;
            }
        }
    }
    __syncthreads();

    // ---- phase B: conv2 (MFMA), h1 from LDS ----
    int lane = threadIdx.x & 63;
    int wave = threadIdx.x >> 6;
    int n16 = lane & 15, quad = lane >> 4;
    int y0w = Y0 + wave * 8;

    short8 wf[18];
#pragma unroll
    for (int tap = 0; tap < 9; tap++)
#pragma unroll
        for (int t = 0; t < 2; t++)
            wf[tap * 2 + t] = *(const short8*)(Wr2 + ((tap * 2 + t) * 16 + n16) * 32 + quad * 8);

    short8 win[3][3];
    auto loadrow = [&](int yy, short8* dst) {
        int ly = yy - (Y0 - 1);   // always in [0,34)
#pragma unroll
        for (int dx = 0; dx < 3; dx++)
            dst[dx] = *(const short8*)(&h1t[ly][n16 + dx][quad * 8]);
    };
    loadrow(y0w - 1, win[0]);
    loadrow(y0w,     win[1]);

    float4v bias[2];
#pragma unroll
    for (int t = 0; t < 2; t++)
        bias[t] = *(const float4v*)(B2 + t * 16 + quad * 4);

    bf16* out = outb + (size_t)b * NN * NN * 32;
#pragma unroll
    for (int i = 0; i < 8; i++) {
        int y = y0w + i;
        loadrow(y + 1, win[(i + 2) % 3]);
        float4v acc[2];
#pragma unroll
        for (int t = 0; t < 2; t++) acc[t] = bias[t];
#pragma unroll
        for (int dy = 0; dy < 3; dy++) {
            short8* row = win[(i + dy) % 3];
#pragma unroll
            for (int dx = 0; dx < 3; dx++) {
                int tap = dy * 3 + dx;
#pragma unroll
                for (int t = 0; t < 2; t++)
                    acc[t] = __builtin_amdgcn_mfma_f32_16x16x32_bf16(wf[tap * 2 + t], row[dx], acc[t], 0, 0, 0);
            }
        }
        bf16* pp = out + ((size_t)y * NN + x0 + n16) * 32 + quad * 4;
#pragma unroll
        for (int t = 0; t < 2; t++) {
            s4v pk;
#pragma unroll
            for (int r = 0; r < 4; r++) {
                float v = fmaxf(acc[t][r], 0.f);
                bf16 h = __float2bfloat16(v);
                pk[r] = *reinterpret_cast<short*>(&h);
            }
            *(s4v*)(pp + t * 16) = pk;
        }
    }
}

// ---- streaming MFMA implicit-GEMM 3x3 conv, HWC bf16 in (32 ci) ----
// OUTF32 path writes YP = addsrc + conv AND the transposed copy YPT.
#define SH 8
template<int NCO, bool RELU, bool HASB, bool OUTF32>
__global__ __launch_bounds__(256) void k_conv_stream(const bf16* __restrict__ inb,
    const bf16* __restrict__ Wr, const float* __restrict__ Bs,
    const float* __restrict__ addsrc, void* __restrict__ outv,
    float* __restrict__ outT)
{
    int lane = threadIdx.x & 63;
    int wave = threadIdx.x >> 6;
    int n16 = lane & 15, quad = lane >> 4;
    int b = blockIdx.z;
    int x0 = blockIdx.x * 16;
    int y0 = (blockIdx.y * 4 + wave) * SH;
    const bf16* in = inb + (size_t)b * NN * NN * 32;

    short8 wf[9 * NCO];
#pragma unroll
    for (int tap = 0; tap < 9; tap++)
#pragma unroll
        for (int t = 0; t < NCO; t++)
            wf[tap * NCO + t] = *(const short8*)(Wr + ((tap * NCO + t) * 16 + n16) * 32 + quad * 8);

    bool vx[3];
#pragma unroll
    for (int dx = 0; dx < 3; dx++) {
        int xx = x0 + n16 + dx - 1;
        vx[dx] = (xx >= 0) && (xx < NN);
    }

    short8 win[3][3];
    auto loadrow = [&](int yy, short8* dst) {
        if (yy >= 0 && yy < NN) {
            const bf16* rowp = in + (size_t)yy * NN * 32;
#pragma unroll
            for (int dx = 0; dx < 3; dx++) {
                short8 v = {};
                if (vx[dx]) v = *(const short8*)(rowp + (x0 + n16 + dx - 1) * 32 + quad * 8);
                dst[dx] = v;
            }
        } else {
            dst[0] = short8{}; dst[1] = short8{}; dst[2] = short8{};
        }
    };
    loadrow(y0 - 1, win[0]);
    loadrow(y0,     win[1]);

    float4v bias[NCO];
#pragma unroll
    for (int t = 0; t < NCO; t++)
        bias[t] = HASB ? *(const float4v*)(Bs + t * 16 + quad * 4) : (float4v){0.f, 0.f, 0.f, 0.f};

#pragma unroll
    for (int i = 0; i < SH; i++) {
        int y = y0 + i;
        loadrow(y + 1, win[(i + 2) % 3]);
        float4v acc[NCO];
#pragma unroll
        for (int t = 0; t < NCO; t++) acc[t] = bias[t];
#pragma unroll
        for (int dy = 0; dy < 3; dy++) {
            short8* row = win[(i + dy) % 3];
#pragma unroll
            for (int dx = 0; dx < 3; dx++) {
                int tap = dy * 3 + dx;
#pragma unroll
                for (int t = 0; t < NCO; t++)
                    acc[t] = __builtin_amdgcn_mfma_f32_16x16x32_bf16(wf[tap * NCO + t], row[dx], acc[t], 0, 0, 0);
            }
        }
        if (OUTF32) {
            float* out = (float*)outv + b * PIMG;
            if (quad == 0) {
                int px = x0 + n16;
                float vv = addsrc[b * PIMG + y * PW + px] + acc[0][0];
                out[y * PW + px] = vv;
                outT[b * PIMG + px * PW + y] = vv;
            }
        } else {
            bf16* out = (bf16*)outv + (size_t)b * NN * NN * 32;
            bf16* pp = out + ((size_t)y * NN + x0 + n16) * 32 + quad * 4;
#pragma unroll
            for (int t = 0; t < NCO; t++) {
                s4v pk;
#pragma unroll
                for (int r = 0; r < 4; r++) {
                    float v = acc[t][r];
                    if (RELU) v = fmaxf(v, 0.f);
                    bf16 h = __float2bfloat16(v);
                    pk[r] = *reinterpret_cast<short*>(&h);
                }
                *(s4v*)(pp + t * 16) = pk;
            }
        }
    }
}

extern "C" void kernel_launch(void* const* d_in, const int* in_sizes, int n_in,
                              void* d_out, int out_size, void* d_ws, size_t ws_size,
                              hipStream_t stream)
{
    const float* x0    = (const float*)d_in[1];
    const float* sg    = (const float*)d_in[2];
    const float* theta = (const float*)d_in[3];
    const float* w1    = (const float*)d_in[5];
    const float* b1    = (const float*)d_in[6];
    const float* w2    = (const float*)d_in[7];
    const float* b2    = (const float*)d_in[8];
    const float* w3    = (const float*)d_in[9];
    const float* b3    = (const float*)d_in[10];
    const float* w4    = (const float*)d_in[11];
    const float* steps = (const float*)d_in[12];

    float* ws = (float*)d_ws;
    float* XP  = ws + O_XP + POFF;    // origin-adjusted padded pointers
    float* YP  = ws + O_YP + POFF;
    float* YPT = ws + O_YPT + POFF;
    float* SP = ws + O_SP;
    float* Q  = ws + O_Q;
    bf16* wr  = (bf16*)(ws + O_WR);
    bf16* h1  = (bf16*)(ws + O_H);
    bf16* h2  = (bf16*)(ws + O_H + H_FLOATS);

    k_prep<<<(2 * PIMG + 255) / 256, 256, 0, stream>>>(theta, w2, w3, w4, x0, ws, wr);

    for (int n = 0; n < NL; n++) {
        // denoiser: fused conv1+2 (XP -> h2), conv3 (h2 -> h1), conv4 (h1 -> YP/YPT)
        k_conv12<<<dim3(32, 16, NB), 256, 0, stream>>>(
            XP, w1 + n * 288, b1 + n * 32, wr + WR2_OFF + n * 9216, b2 + n * 32, h2);
        k_conv_stream<2, true, true, false><<<dim3(32, 16, NB), 256, 0, stream>>>(
            h2, wr + WR3_OFF + n * 9216, b3 + n * 32, nullptr, h1, nullptr);
        k_conv_stream<1, false, false, true><<<dim3(32, 16, NB), 256, 0, stream>>>(
            h1, wr + WR4_OFF + n * 4608, nullptr, XP, YP, YPT);

        // fused physics path (linearity): XP = YP + steps[n]*bp(sino - F(R(YP)))
        k_radon<<<dim3((ND + 3) / 4, NA, NB), 256, 0, stream>>>(YP, YPT, ws, SP);
        k_filter<<<dim3(3, NB * NA), 256, 0, stream>>>(SP, sg, Q);
        k_backproj_update<<<dim3(32, 32, NB), 256, 0, stream>>>(
            Q, YP, ws, steps, n, XP, (n == NL - 1) ? (float*)d_out : nullptr);
    }
}

// Round 17
// 410.260 us; speedup vs baseline: 1.0683x; 1.0185x over previous
//
#include <hip/hip_runtime.h>
#include <hip/hip_bf16.h>

typedef __hip_bfloat16 bf16;
typedef __attribute__((ext_vector_type(8))) short short8;
typedef __attribute__((ext_vector_type(4))) short s4v;
typedef __attribute__((ext_vector_type(4))) float float4v;

#define NN 512      // image N
#define NA 30       // angles
#define ND 729      // detectors
#define NB 2        // batch
#define NL 3        // iterations
#define BNN (NB*NN*NN)     // 524288
#define BAD (NB*NA*ND)     // 43740

// padded image layout: PH x PW, logical (0,0) at physical (2,2)
#define PW 520
#define PH 516
#define PIMG (PH*PW)       // 268320
#define POFF (2*PW + 2)    // 1042

// ---- workspace float offsets ----
#define O_CS  0
#define O_SN  32
#define O_ICS 64                      // 1/cs per angle
#define O_ISN 96                      // -1/sn per angle
#define O_XP  128                     // 2*PIMG  (current X, padded)
#define O_YP  (O_XP + 2*PIMG)         // 2*PIMG  (Y = X + noise, padded)
#define O_YPT (O_YP + 2*PIMG)         // 2*PIMG  (transposed Y, padded)
#define O_SP  (O_YPT + 2*PIMG)        // BAD
#define O_Q   (O_SP + BAD)            // BAD
#define O_WR  (O_Q + BAD)             // bf16 region: 69120 bf16 = 34560 floats
#define O_H   (((O_WR + 34560) + 15) & ~15)
#define H_FLOATS (NB * 32 * NN * NN / 2)

// repacked weight bf16 offsets within WR region
#define WR2_OFF 0                   // [n][tap][co32][ci32] : 3*9216
#define WR3_OFF 27648               // 3*9216
#define WR4_OFF 55296               // [n][tap][co16][ci32] : 3*4608 (co>0 zero)

// unaligned 8B load (pair of adjacent floats) -> global_load_dwordx2
__device__ __forceinline__ float2 ld2u(const float* p)
{
    float2 r;
    __builtin_memcpy(&r, p, 8);
    return r;
}

// ---- setup: angles + reciprocals + weight repack + image padding, one kernel ----
__global__ void k_prep(const float* __restrict__ theta,
                       const float* __restrict__ w2, const float* __restrict__ w3,
                       const float* __restrict__ w4, const float* __restrict__ x0,
                       float* __restrict__ ws, bf16* __restrict__ wr)
{
    int idx = blockIdx.x * 256 + threadIdx.x;
    if (idx < NA) {
        float t = theta[idx];
        float cs = cosf(t), sn = sinf(t);
        ws[O_CS + idx] = cs;
        ws[O_SN + idx] = sn;
        ws[O_ICS + idx] = 1.0f / cs;      // +-inf ok
        ws[O_ISN + idx] = -1.0f / sn;     // +-inf ok
    }
    if (idx < 2 * 27648) {
        const float* w = (idx < 27648) ? w2 : w3;
        int base = (idx < 27648) ? WR2_OFF : WR3_OFF;
        int r = idx % 27648;
        int n = r / 9216; int r2 = r % 9216;
        int tap = r2 / 1024; int r3 = r2 % 1024;
        int co = r3 / 32, ci = r3 % 32;
        wr[base + r] = __float2bfloat16(w[n * 9216 + (co * 32 + ci) * 9 + tap]);
    } else if (idx < 2 * 27648 + 3 * 4608) {
        int r = idx - 2 * 27648;
        int n = r / 4608; int r2 = r % 4608;
        int tap = r2 / 512; int r3 = r2 % 512;
        int co = r3 / 32, ci = r3 % 32;
        float v = (co == 0) ? w4[n * 288 + ci * 9 + tap] : 0.f;
        wr[WR4_OFF + r] = __float2bfloat16(v);
    }
    if (idx < 2 * PIMG) {
        int b = idx / PIMG, p = idx % PIMG;
        int y = p / PW, x = p % PW;
        bool interior = (y >= 2 && y < 2 + NN && x >= 2 && x < 2 + NN);
        float v = interior ? x0[b * NN * NN + (y - 2) * NN + (x - 2)] : 0.f;
        ws[O_XP + idx] = v;
        if (!interior) {
            ws[O_YP + idx] = 0.f;
            ws[O_YPT + idx] = 0.f;
        }
    }
}

// intersect t-interval with constraint lo < A + tc*coef < hi, via inv = 1/coef
__device__ __forceinline__ void isect2(float A, float inv, float lo, float hi,
                                       float& tlo, float& thi)
{
    float a = (lo - A) * inv, b = (hi - A) * inv;
    tlo = fmaxf(tlo, fminf(a, b));   // NaN (0*inf) dropped by fmin/fmax -> safe
    thi = fminf(thi, fmaxf(a, b));
}

// ---- radon forward: TWO adjacent rays per wave, 32 t-lanes each ----
// Adjacent rays share cache lines (1 px apart) -> lines/load ~ 32*min(|cs|,|sn|).
// Angle-adaptive layout (normal vs transposed copy) keeps min() the row rate.
__global__ __launch_bounds__(256) void k_radon(const float* __restrict__ img,
    const float* __restrict__ imgT, const float* __restrict__ ws,
    float* __restrict__ out)
{
    int b = blockIdx.z, a = blockIdx.y;
    int wave = threadIdx.x >> 6;
    int lane = threadIdx.x & 63;
    int half = lane >> 5, tl = lane & 31;
    int s = blockIdx.x * 8 + wave * 2 + half;
    float cs = ws[O_CS + a], sn = ws[O_SN + a];
    float ics = ws[O_ICS + a], isn = ws[O_ISN + a];
    float s_c = (float)s - 364.0f;
    float A_r = 255.5f + s_c * sn;    // r(t) = A_r + tc*cs
    float A_c = 255.5f + s_c * cs;    // c(t) = A_c - tc*sn

    float tlo = -1e9f, thi = 1e9f;
    isect2(A_r, ics, -1.0f, 512.0f, tlo, thi);
    isect2(A_c, isn, -1.0f, 512.0f, tlo, thi);
    float t0f = fmaxf(tlo + 364.0f, 0.0f);
    float t1f = fminf(thi + 364.0f, 728.0f);

    bool useT = fabsf(cs) >= fabsf(sn);   // wave-uniform
    const float* im = (useT ? imgT : img) + b * PIMG;

    float acc = 0.f;
    if (s < ND && t0f <= t1f) {
        int tb = (int)ceilf(t0f);
        int te = (int)floorf(t1f);
#pragma unroll 2
        for (int t = tb + tl; t <= te; t += 32) {
            float tc = (float)t - 364.0f;
            float r = fmaf(tc, cs, A_r);
            float c = fmaf(-tc, sn, A_c);
            float rf = floorf(r), cf = floorf(c);
            float dr = r - rf, dc = c - cf;
            int irr = (int)rf, icc = (int)cf;
            int idx = useT ? (icc * PW + irr) : (irr * PW + icc);
            float da = useT ? dr : dc;
            float db = useT ? dc : dr;
            float2 p1 = ld2u(im + idx);
            float2 p2 = ld2u(im + idx + PW);
            float u = fmaf(da, p1.y - p1.x, p1.x);
            float w = fmaf(da, p2.y - p2.x, p2.x);
            acc = fmaf(db, w - u, acc + u);
        }
    }
    // butterfly within each 32-lane half (masks <= 16 never cross the half)
    acc += __shfl_xor(acc, 16, 64);
    acc += __shfl_xor(acc, 8, 64);
    acc += __shfl_xor(acc, 4, 64);
    acc += __shfl_xor(acc, 2, 64);
    acc += __shfl_xor(acc, 1, 64);
    if (tl == 0 && s < ND) out[(b * NA + a) * ND + s] = acc;
}

// ---- ramp filter as direct odd-tap convolution: q = sino - scale*conv(sp) ----
__global__ void k_filter(const float* __restrict__ sp, const float* __restrict__ sino,
                         float* __restrict__ q)
{
    __shared__ float row[ND];
    __shared__ float taps[364];
    int ba = blockIdx.y;
    const float* src = sp + ba * ND;
    for (int i = threadIdx.x; i < ND; i += 256) row[i] = src[i];
    const float PI2 = 9.86960440108936f;
    for (int i = threadIdx.x; i < 364; i += 256) {
        float m = (float)(2 * i + 1);
        taps[i] = -2.0f / (PI2 * m * m);
    }
    __syncthreads();
    const float scale = 0.0523598775598299f;  // pi/(2A)
    int d = blockIdx.x * 256 + threadIdx.x;
    if (d < ND) {
        float g0 = 0.5f * row[d], g1 = 0.f;
#pragma unroll 4
        for (int j = 0; j < 364; j += 2) {
            int m0 = 2 * j + 1, m1 = 2 * j + 3;
            float l0 = (d - m0 >= 0) ? row[d - m0] : 0.f;
            float r0 = (d + m0 < ND) ? row[d + m0] : 0.f;
            g0 = fmaf(taps[j], l0 + r0, g0);
            float l1 = (d - m1 >= 0) ? row[d - m1] : 0.f;
            float r1 = (d + m1 < ND) ? row[d + m1] : 0.f;
            g1 = fmaf(taps[j + 1], l1 + r1, g1);
        }
        q[ba * ND + d] = sino[ba * ND + d] - scale * (g0 + g1);
    }
}

// ---- LDS-tiled backprojection + update:  out = src1 + steps[n]*bp(q) ----
__global__ __launch_bounds__(256) void k_backproj_update(const float* __restrict__ q,
    const float* __restrict__ src1, const float* __restrict__ ws,
    const float* __restrict__ steps, int n, float* __restrict__ out,
    float* __restrict__ outcopy)
{
    __shared__ float qt[NA][28];
    __shared__ int dmin_s[NA];
    int b = blockIdx.z;
    int x0 = blockIdx.x * 16, y0 = blockIdx.y * 16;
    int tid = threadIdx.x;
    int lx = tid & 15, ly = tid >> 4;
    const float* qb = q + b * NA * ND;

    for (int idx = tid; idx < NA * 26; idx += 256) {
        int a = idx / 26, j = idx % 26;
        float cs = ws[O_CS + a], sn = ws[O_SN + a];
        float f00 = fmaf(cs, (float)x0 - 255.5f, fmaf(sn, (float)y0 - 255.5f, 364.0f));
        float fmn = f00 + fminf(cs * 15.f, 0.f) + fminf(sn * 15.f, 0.f);
        int dm = (int)floorf(fmn);
        if (j == 0) dmin_s[a] = dm;
        int d = dm + j;
        qt[a][j] = (d >= 0 && d < ND) ? qb[a * ND + d] : 0.f;
    }
    __syncthreads();

    float xc = (float)(x0 + lx) - 255.5f, yc = (float)(y0 + ly) - 255.5f;
    float acc = 0.f;
#pragma unroll
    for (int a = 0; a < NA; a++) {
        float cs = ws[O_CS + a], sn = ws[O_SN + a];
        float f = fmaf(cs, xc, fmaf(sn, yc, 364.0f));
        float lf = floorf(f);
        float w = f - lf;
        int j = (int)lf - dmin_s[a];
        float v0 = qt[a][j], v1 = qt[a][j + 1];
        acc = fmaf(v0, 1.0f - w, fmaf(v1, w, acc));
    }
    int pidx = b * PIMG + (y0 + ly) * PW + (x0 + lx);
    float v = fmaf(steps[n], acc, src1[pidx]);
    out[pidx] = v;
    if (outcopy) {
        int fidx = b * NN * NN + (y0 + ly) * NN + (x0 + lx);
        outcopy[fidx] = v;
        outcopy[fidx + BNN] = v;
        outcopy[fidx + 2 * BNN] = v;
    }
}

// ---- FUSED conv1+conv2: XP -> (h1 halo tile in LDS) -> h2 (HWC bf16 global) ----
__global__ __launch_bounds__(256) void k_conv12(const float* __restrict__ XPb,
    const float* __restrict__ W1, const float* __restrict__ B1,
    const bf16* __restrict__ Wr2, const float* __restrict__ B2,
    bf16* __restrict__ outb)
{
    __shared__ bf16 h1t[34][18][32];
    int b = blockIdx.z;
    int x0 = blockIdx.x * 16;
    int Y0 = blockIdx.y * 32;
    const float* in = XPb + b * PIMG;      // origin-adjusted padded

    // ---- phase A: h1 on halo [Y0-1, Y0+33) x [x0-1, x0+17) ----
    for (int p = threadIdx.x; p < 34 * 18; p += 256) {
        int yy = p / 18, xx = p % 18;
        int gy = Y0 + yy - 1, gx = x0 + xx - 1;
        if (gy < 0 || gy >= NN || gx < 0 || gx >= NN) {
#pragma unroll
            for (int g = 0; g < 4; g++)
                *(short8*)(&h1t[yy][xx][g * 8]) = short8{};
        } else {
            float v[9];
#pragma unroll
            for (int dy = 0; dy < 3; dy++)
#pragma unroll
                for (int dx = 0; dx < 3; dx++)
                    v[dy * 3 + dx] = in[(gy + dy - 1) * PW + (gx + dx - 1)];
#pragma unroll
            for (int g = 0; g < 4; g++) {
                short8 pk;
#pragma unroll
                for (int j = 0; j < 8; j++) {
                    int co = g * 8 + j;
                    float a = B1[co];
                    const float* w = W1 + co * 9;   // block-uniform -> s_load
#pragma unroll
                    for (int k = 0; k < 9; k++) a = fmaf(v[k], w[k], a);
                    a = fmaxf(a, 0.f);
                    bf16 h = __float2bfloat16(a);
                    pk[j] = *reinterpret_cast<short*>(&h);
                }
                *(short8*)(&h1t[yy][xx][g * 8]) = pk;
            }
        }
    }
    __syncthreads();

    // ---- phase B: conv2 (MFMA), h1 from LDS ----
    int lane = threadIdx.x & 63;
    int wave = threadIdx.x >> 6;
    int n16 = lane & 15, quad = lane >> 4;
    int y0w = Y0 + wave * 8;

    short8 wf[18];
#pragma unroll
    for (int tap = 0; tap < 9; tap++)
#pragma unroll
        for (int t = 0; t < 2; t++)
            wf[tap * 2 + t] = *(const short8*)(Wr2 + ((tap * 2 + t) * 16 + n16) * 32 + quad * 8);

    short8 win[3][3];
    auto loadrow = [&](int yy, short8* dst) {
        int ly = yy - (Y0 - 1);   // always in [0,34)
#pragma unroll
        for (int dx = 0; dx < 3; dx++)
            dst[dx] = *(const short8*)(&h1t[ly][n16 + dx][quad * 8]);
    };
    loadrow(y0w - 1, win[0]);
    loadrow(y0w,     win[1]);

    float4v bias[2];
#pragma unroll
    for (int t = 0; t < 2; t++)
        bias[t] = *(const float4v*)(B2 + t * 16 + quad * 4);

    bf16* out = outb + (size_t)b * NN * NN * 32;
#pragma unroll
    for (int i = 0; i < 8; i++) {
        int y = y0w + i;
        loadrow(y + 1, win[(i + 2) % 3]);
        float4v acc[2];
#pragma unroll
        for (int t = 0; t < 2; t++) acc[t] = bias[t];
#pragma unroll
        for (int dy = 0; dy < 3; dy++) {
            short8* row = win[(i + dy) % 3];
#pragma unroll
            for (int dx = 0; dx < 3; dx++) {
                int tap = dy * 3 + dx;
#pragma unroll
                for (int t = 0; t < 2; t++)
                    acc[t] = __builtin_amdgcn_mfma_f32_16x16x32_bf16(wf[tap * 2 + t], row[dx], acc[t], 0, 0, 0);
            }
        }
        bf16* pp = out + ((size_t)y * NN + x0 + n16) * 32 + quad * 4;
#pragma unroll
        for (int t = 0; t < 2; t++) {
            s4v pk;
#pragma unroll
            for (int r = 0; r < 4; r++) {
                float v = fmaxf(acc[t][r], 0.f);
                bf16 h = __float2bfloat16(v);
                pk[r] = *reinterpret_cast<short*>(&h);
            }
            *(s4v*)(pp + t * 16) = pk;
        }
    }
}

// ---- streaming MFMA implicit-GEMM 3x3 conv, HWC bf16 in (32 ci) ----
// OUTF32 path writes YP = addsrc + conv AND the transposed copy YPT.
#define SH 8
template<int NCO, bool RELU, bool HASB, bool OUTF32>
__global__ __launch_bounds__(256) void k_conv_stream(const bf16* __restrict__ inb,
    const bf16* __restrict__ Wr, const float* __restrict__ Bs,
    const float* __restrict__ addsrc, void* __restrict__ outv,
    float* __restrict__ outT)
{
    int lane = threadIdx.x & 63;
    int wave = threadIdx.x >> 6;
    int n16 = lane & 15, quad = lane >> 4;
    int b = blockIdx.z;
    int x0 = blockIdx.x * 16;
    int y0 = (blockIdx.y * 4 + wave) * SH;
    const bf16* in = inb + (size_t)b * NN * NN * 32;

    short8 wf[9 * NCO];
#pragma unroll
    for (int tap = 0; tap < 9; tap++)
#pragma unroll
        for (int t = 0; t < NCO; t++)
            wf[tap * NCO + t] = *(const short8*)(Wr + ((tap * NCO + t) * 16 + n16) * 32 + quad * 8);

    bool vx[3];
#pragma unroll
    for (int dx = 0; dx < 3; dx++) {
        int xx = x0 + n16 + dx - 1;
        vx[dx] = (xx >= 0) && (xx < NN);
    }

    short8 win[3][3];
    auto loadrow = [&](int yy, short8* dst) {
        if (yy >= 0 && yy < NN) {
            const bf16* rowp = in + (size_t)yy * NN * 32;
#pragma unroll
            for (int dx = 0; dx < 3; dx++) {
                short8 v = {};
                if (vx[dx]) v = *(const short8*)(rowp + (x0 + n16 + dx - 1) * 32 + quad * 8);
                dst[dx] = v;
            }
        } else {
            dst[0] = short8{}; dst[1] = short8{}; dst[2] = short8{};
        }
    };
    loadrow(y0 - 1, win[0]);
    loadrow(y0,     win[1]);

    float4v bias[NCO];
#pragma unroll
    for (int t = 0; t < NCO; t++)
        bias[t] = HASB ? *(const float4v*)(Bs + t * 16 + quad * 4) : (float4v){0.f, 0.f, 0.f, 0.f};

#pragma unroll
    for (int i = 0; i < SH; i++) {
        int y = y0 + i;
        loadrow(y + 1, win[(i + 2) % 3]);
        float4v acc[NCO];
#pragma unroll
        for (int t = 0; t < NCO; t++) acc[t] = bias[t];
#pragma unroll
        for (int dy = 0; dy < 3; dy++) {
            short8* row = win[(i + dy) % 3];
#pragma unroll
            for (int dx = 0; dx < 3; dx++) {
                int tap = dy * 3 + dx;
#pragma unroll
                for (int t = 0; t < NCO; t++)
                    acc[t] = __builtin_amdgcn_mfma_f32_16x16x32_bf16(wf[tap * NCO + t], row[dx], acc[t], 0, 0, 0);
            }
        }
        if (OUTF32) {
            float* out = (float*)outv + b * PIMG;
            if (quad == 0) {
                int px = x0 + n16;
                float vv = addsrc[b * PIMG + y * PW + px] + acc[0][0];
                out[y * PW + px] = vv;
                outT[b * PIMG + px * PW + y] = vv;
            }
        } else {
            bf16* out = (bf16*)outv + (size_t)b * NN * NN * 32;
            bf16* pp = out + ((size_t)y * NN + x0 + n16) * 32 + quad * 4;
#pragma unroll
            for (int t = 0; t < NCO; t++) {
                s4v pk;
#pragma unroll
                for (int r = 0; r < 4; r++) {
                    float v = acc[t][r];
                    if (RELU) v = fmaxf(v, 0.f);
                    bf16 h = __float2bfloat16(v);
                    pk[r] = *reinterpret_cast<short*>(&h);
                }
                *(s4v*)(pp + t * 16) = pk;
            }
        }
    }
}

extern "C" void kernel_launch(void* const* d_in, const int* in_sizes, int n_in,
                              void* d_out, int out_size, void* d_ws, size_t ws_size,
                              hipStream_t stream)
{
    const float* x0    = (const float*)d_in[1];
    const float* sg    = (const float*)d_in[2];
    const float* theta = (const float*)d_in[3];
    const float* w1    = (const float*)d_in[5];
    const float* b1    = (const float*)d_in[6];
    const float* w2    = (const float*)d_in[7];
    const float* b2    = (const float*)d_in[8];
    const float* w3    = (const float*)d_in[9];
    const float* b3    = (const float*)d_in[10];
    const float* w4    = (const float*)d_in[11];
    const float* steps = (const float*)d_in[12];

    float* ws = (float*)d_ws;
    float* XP  = ws + O_XP + POFF;    // origin-adjusted padded pointers
    float* YP  = ws + O_YP + POFF;
    float* YPT = ws + O_YPT + POFF;
    float* SP = ws + O_SP;
    float* Q  = ws + O_Q;
    bf16* wr  = (bf16*)(ws + O_WR);
    bf16* h1  = (bf16*)(ws + O_H);
    bf16* h2  = (bf16*)(ws + O_H + H_FLOATS);

    k_prep<<<(2 * PIMG + 255) / 256, 256, 0, stream>>>(theta, w2, w3, w4, x0, ws, wr);

    for (int n = 0; n < NL; n++) {
        // denoiser: fused conv1+2 (XP -> h2), conv3 (h2 -> h1), conv4 (h1 -> YP/YPT)
        k_conv12<<<dim3(32, 16, NB), 256, 0, stream>>>(
            XP, w1 + n * 288, b1 + n * 32, wr + WR2_OFF + n * 9216, b2 + n * 32, h2);
        k_conv_stream<2, true, true, false><<<dim3(32, 16, NB), 256, 0, stream>>>(
            h2, wr + WR3_OFF + n * 9216, b3 + n * 32, nullptr, h1, nullptr);
        k_conv_stream<1, false, false, true><<<dim3(32, 16, NB), 256, 0, stream>>>(
            h1, wr + WR4_OFF + n * 4608, nullptr, XP, YP, YPT);

        // fused physics path (linearity): XP = YP + steps[n]*bp(sino - F(R(YP)))
        k_radon<<<dim3((ND + 7) / 8, NA, NB), 256, 0, stream>>>(YP, YPT, ws, SP);
        k_filter<<<dim3(3, NB * NA), 256, 0, stream>>>(SP, sg, Q);
        k_backproj_update<<<dim3(32, 32, NB), 256, 0, stream>>>(
            Q, YP, ws, steps, n, XP, (n == NL - 1) ? (float*)d_out : nullptr);
    }
}